// Round 3
// baseline (655.111 us; speedup 1.0000x reference)
//
#include <hip/hip_runtime.h>

#define NUM_Q 4096
#define MAX_STEP 200
#define NBATCH 64
#define NT 199                    // MAX_STEP - 1
#define NROWS (NBATCH * NT)       // 12736 rows
#define EPS 1e-8f
#define NQ4 (NUM_Q / 4)           // 1024 float4 per row

// Stage 1: one block per (b,t) row. 256 threads x 4 float4-groups per stream.
// All 12 float4 loads are issued up front (full unroll) -> max per-wave MLP,
// no per-iteration division or waitcnt drain. Partial sum -> blockSums[row].
__global__ __launch_bounds__(256) void loss_main(const float* __restrict__ pred,
                                                 const float* __restrict__ batch,
                                                 float* __restrict__ blockSums) {
    const int row = blockIdx.x;           // 0 .. NROWS-1
    const int b = row / NT;               // scalar magic-mul, once per block
    const int t = row - b * NT;

    const float4* __restrict__ predRow = (const float4*)(pred + (size_t)row * NUM_Q);
    const float*  batchRow = batch + ((size_t)(b * MAX_STEP + t + 1) << 13);
    const float4* __restrict__ mqRow  = (const float4*)(batchRow);
    const float4* __restrict__ mnqRow = (const float4*)(batchRow + NUM_Q);

    // Issue all 12 loads before any dependent math.
    float4 p0  = predRow[threadIdx.x];
    float4 p1  = predRow[threadIdx.x + 256];
    float4 p2  = predRow[threadIdx.x + 512];
    float4 p3  = predRow[threadIdx.x + 768];
    float4 q0  = mqRow[threadIdx.x];
    float4 q1  = mqRow[threadIdx.x + 256];
    float4 q2  = mqRow[threadIdx.x + 512];
    float4 q3  = mqRow[threadIdx.x + 768];
    float4 n0  = mnqRow[threadIdx.x];
    float4 n1  = mnqRow[threadIdx.x + 256];
    float4 n2  = mnqRow[threadIdx.x + 512];
    float4 n3  = mnqRow[threadIdx.x + 768];

    float acc = 0.0f;
    #define TERM(q, n, p) \
        acc += q.x * __logf(p.x + EPS) + n.x * __logf(1.0f - p.x + EPS); \
        acc += q.y * __logf(p.y + EPS) + n.y * __logf(1.0f - p.y + EPS); \
        acc += q.z * __logf(p.z + EPS) + n.z * __logf(1.0f - p.z + EPS); \
        acc += q.w * __logf(p.w + EPS) + n.w * __logf(1.0f - p.w + EPS);
    TERM(q0, n0, p0)
    TERM(q1, n1, p1)
    TERM(q2, n2, p2)
    TERM(q3, n3, p3)
    #undef TERM

    // 64-lane wave reduction
    #pragma unroll
    for (int off = 32; off > 0; off >>= 1)
        acc += __shfl_down(acc, off, 64);

    __shared__ float smem[4];
    const int lane = threadIdx.x & 63;
    const int wave = threadIdx.x >> 6;
    if (lane == 0) smem[wave] = acc;
    __syncthreads();
    if (threadIdx.x == 0)
        blockSums[row] = smem[0] + smem[1] + smem[2] + smem[3];
}

// Stage 2: one block reduces the 12736 partials; writes -sum (the loss).
__global__ __launch_bounds__(256) void loss_final(const float* __restrict__ blockSums,
                                                  float* __restrict__ out) {
    float acc = 0.0f;
    for (int i = threadIdx.x; i < NROWS; i += 256)
        acc += blockSums[i];

    #pragma unroll
    for (int off = 32; off > 0; off >>= 1)
        acc += __shfl_down(acc, off, 64);

    __shared__ float smem[4];
    const int lane = threadIdx.x & 63;
    const int wave = threadIdx.x >> 6;
    if (lane == 0) smem[wave] = acc;
    __syncthreads();
    if (threadIdx.x == 0)
        out[0] = -(smem[0] + smem[1] + smem[2] + smem[3]);
}

extern "C" void kernel_launch(void* const* d_in, const int* in_sizes, int n_in,
                              void* d_out, int out_size, void* d_ws, size_t ws_size,
                              hipStream_t stream) {
    const float* pred  = (const float*)d_in[0];
    const float* batch = (const float*)d_in[1];
    float* blockSums   = (float*)d_ws;     // ~51 KB of workspace
    float* out         = (float*)d_out;

    loss_main<<<NROWS, 256, 0, stream>>>(pred, batch, blockSums);
    loss_final<<<1, 256, 0, stream>>>(blockSums, out);
}

// Round 5
// 616.537 us; speedup vs baseline: 1.0626x; 1.0626x over previous
//
#include <hip/hip_runtime.h>

#define NUM_Q 4096
#define MAX_STEP 200
#define NBATCH 64
#define NT 199                          // MAX_STEP - 1
#define NROWS (NBATCH * NT)             // 12736
#define EPS 1e-8f
#define NQ4 (NUM_Q / 4)                 // 1024 float4 per row
#define TOTAL_V4 (NROWS * NQ4)          // 199 * 65536 = 13,041,664
#define NBLK 6368                       // TOTAL_V4 / (NBLK*256) == 8 exactly
#define ITERS (TOTAL_V4 / (NBLK * 256)) // 8, no tail guard needed

// Native vector type — __builtin_nontemporal_load requires a real vector,
// not HIP's struct-based float4.
typedef float vf4 __attribute__((ext_vector_type(4)));

// Stage 1: flat grid-stride with compile-time-exact trip count (8) and a
// depth-2 software pipeline: iteration i+1's three nontemporal float4 loads
// are issued before iteration i's log chain, so waits are vmcnt(3) not
// vmcnt(0) and loads stay in flight across the transcendental compute.
__global__ __launch_bounds__(256) void loss_main(const float* __restrict__ pred,
                                                 const float* __restrict__ batch,
                                                 float* __restrict__ blockSums) {
    const vf4* __restrict__ pred4 = (const vf4*)pred;
    const int stride = NBLK * 256;
    int g = blockIdx.x * 256 + threadIdx.x;

    float acc = 0.0f;

    // Prefetch iteration 0.
    vf4 p, q, n;
    {
        const int row = g >> 10, r = g & (NQ4 - 1);
        const int b = row / NT, t = row - b * NT;
        const vf4* __restrict__ bq =
            (const vf4*)(batch + ((size_t)(b * MAX_STEP + t + 1) << 13));
        p = __builtin_nontemporal_load(&pred4[g]);
        q = __builtin_nontemporal_load(&bq[r]);
        n = __builtin_nontemporal_load(&bq[r + NQ4]);
    }

    #pragma unroll
    for (int i = 0; i < ITERS; ++i) {
        vf4 p2 = {0,0,0,0}, q2 = {0,0,0,0}, n2 = {0,0,0,0};
        const int gn = g + stride;
        if (i + 1 < ITERS) {            // compile-time resolved (full unroll)
            const int row = gn >> 10, r = gn & (NQ4 - 1);
            const int b = row / NT, t = row - b * NT;
            const vf4* __restrict__ bq =
                (const vf4*)(batch + ((size_t)(b * MAX_STEP + t + 1) << 13));
            p2 = __builtin_nontemporal_load(&pred4[gn]);
            q2 = __builtin_nontemporal_load(&bq[r]);
            n2 = __builtin_nontemporal_load(&bq[r + NQ4]);
        }
        acc += q.x * __logf(p.x + EPS) + n.x * __logf(1.0f - p.x + EPS);
        acc += q.y * __logf(p.y + EPS) + n.y * __logf(1.0f - p.y + EPS);
        acc += q.z * __logf(p.z + EPS) + n.z * __logf(1.0f - p.z + EPS);
        acc += q.w * __logf(p.w + EPS) + n.w * __logf(1.0f - p.w + EPS);
        p = p2; q = q2; n = n2;
        g = gn;
    }

    // 64-lane wave reduction
    #pragma unroll
    for (int off = 32; off > 0; off >>= 1)
        acc += __shfl_down(acc, off, 64);

    __shared__ float smem[4];
    const int lane = threadIdx.x & 63;
    const int wave = threadIdx.x >> 6;
    if (lane == 0) smem[wave] = acc;
    __syncthreads();
    if (threadIdx.x == 0)
        blockSums[blockIdx.x] = smem[0] + smem[1] + smem[2] + smem[3];
}

// Stage 2: one block reduces the NBLK partials; writes -sum (the loss).
__global__ __launch_bounds__(256) void loss_final(const float* __restrict__ blockSums,
                                                  float* __restrict__ out) {
    float acc = 0.0f;
    for (int i = threadIdx.x; i < NBLK; i += 256)
        acc += blockSums[i];

    #pragma unroll
    for (int off = 32; off > 0; off >>= 1)
        acc += __shfl_down(acc, off, 64);

    __shared__ float smem[4];
    const int lane = threadIdx.x & 63;
    const int wave = threadIdx.x >> 6;
    if (lane == 0) smem[wave] = acc;
    __syncthreads();
    if (threadIdx.x == 0)
        out[0] = -(smem[0] + smem[1] + smem[2] + smem[3]);
}

extern "C" void kernel_launch(void* const* d_in, const int* in_sizes, int n_in,
                              void* d_out, int out_size, void* d_ws, size_t ws_size,
                              hipStream_t stream) {
    const float* pred  = (const float*)d_in[0];
    const float* batch = (const float*)d_in[1];
    float* blockSums   = (float*)d_ws;     // ~25 KB of workspace
    float* out         = (float*)d_out;

    loss_main<<<NBLK, 256, 0, stream>>>(pred, batch, blockSums);
    loss_final<<<1, 256, 0, stream>>>(blockSums, out);
}